// Round 8
// baseline (220.193 us; speedup 1.0000x reference)
//
#include <hip/hip_runtime.h>
#include <hip/hip_bf16.h>

#define S_LEN 2048
#define DM 1024
#define NB 4

typedef __attribute__((ext_vector_type(8))) short short8;
typedef __attribute__((ext_vector_type(4))) short short4v;
typedef __attribute__((ext_vector_type(4))) float floatx4;

__device__ inline short f2bf(float f) {
    union { float f; unsigned u; } v; v.f = f;
    unsigned r = 0x7fffu + ((v.u >> 16) & 1u);
    return (short)((v.u + r) >> 16);
}

// async global->LDS 16B per lane; lds dest must be wave-uniform base (+lane*16 by HW)
__device__ inline void load16(const short* g, short* l) {
    __builtin_amdgcn_global_load_lds(
        (const __attribute__((address_space(1))) void*)g,
        (__attribute__((address_space(3))) void*)l,
        16, 0, 0);
}

// ---------------- BK=128 GEMM core (pv; r4-proven) -------------------------
__device__ inline void gemm_core128(const short* __restrict__ A,
                                    const short* __restrict__ Bt,
                                    int lda, int ldb, int kLen,
                                    int m0, int n0, floatx4 acc[4][4],
                                    short* As, short* Bs) {
    const int tid  = threadIdx.x;
    const int lane = tid & 63;
    const int wave = tid >> 6;
    const int wr   = (wave >> 1) * 64;
    const int wc   = (wave & 1) * 64;
    const int quad = lane >> 4;
    const int l16  = lane & 15;

    const int srow = tid >> 4;
    const int g    = (tid & 15) ^ srow;
    const short* gA0 = A  + (size_t)(m0 + srow) * lda + g * 8;
    const short* gB0 = Bt + (size_t)(n0 + srow) * ldb + g * 8;
    short* lA0 = &As[wave * 512];
    short* lB0 = &Bs[wave * 512];

    const short* fa[4]; const short* fb[4];
#pragma unroll
    for (int h = 0; h < 4; h++) {
        int sw = ((h * 4 + quad) ^ l16) * 8;
        fa[h] = &As[(wr + l16) * 128 + sw];
        fb[h] = &Bs[(wc + l16) * 128 + sw];
    }

    for (int k0 = 0; k0 < kLen; k0 += 128) {
#pragma unroll
        for (int c = 0; c < 8; c++) load16(gA0 + (size_t)c * 16 * lda, lA0 + c * 2048);
#pragma unroll
        for (int c = 0; c < 8; c++) load16(gB0 + (size_t)c * 16 * ldb, lB0 + c * 2048);
        gA0 += 128; gB0 += 128;
        __syncthreads();

#pragma unroll
        for (int h = 0; h < 4; h++) {
            short8 af[4], bf[4];
#pragma unroll
            for (int t = 0; t < 4; t++) af[t] = *(const short8*)(fa[h] + t * 2048);
#pragma unroll
            for (int t = 0; t < 4; t++) bf[t] = *(const short8*)(fb[h] + t * 2048);
#pragma unroll
            for (int mt = 0; mt < 4; mt++)
#pragma unroll
                for (int nt = 0; nt < 4; nt++)
                    acc[mt][nt] = __builtin_amdgcn_mfma_f32_16x16x32_bf16(
                        af[mt], bf[nt], acc[mt][nt], 0, 0, 0);
        }
        __syncthreads();
    }
}

// ---------------- merged prep: Wt transpose+cast, x cast -------------------
__global__ void prep(const float* __restrict__ x,
                     const float* __restrict__ Wq, const float* __restrict__ Wk,
                     const float* __restrict__ Wv,
                     short* __restrict__ xb, short* __restrict__ Wt) {
    __shared__ float t[64][65];
    int bid = blockIdx.x, tid = threadIdx.x;
    if (bid < 768) {
        // W [k][n] fp32 -> Wt [n][k] bf16 (64x64 tiles)
        int w = bid >> 8, tl = bid & 255;
        const float* W = (w == 0) ? Wq : (w == 1) ? Wk : Wv;
        short* out = Wt + (size_t)w * DM * DM;
        int bx = (tl & 15) * 64;   // n
        int by = (tl >> 4) * 64;   // k
        int tx = tid & 63, ty = tid >> 6;
        for (int r = ty; r < 64; r += 4)
            t[r][tx] = W[(size_t)(by + r) * DM + bx + tx];
        __syncthreads();
        for (int r = ty; r < 64; r += 4)
            out[(size_t)(bx + r) * DM + by + tx] = f2bf(t[tx][r]);
    } else {
        // x fp32 -> bf16, float4-wide
        int i = (bid - 768) * 256 + tid;
        float4 v = ((const float4*)x)[i];
        short4v o;
        o.x = f2bf(v.x); o.y = f2bf(v.y); o.z = f2bf(v.z); o.w = f2bf(v.w);
        ((short4v*)xb)[i] = o;
    }
}

// ---------------- fused QKV GEMM v3: BM=256, B double-buffered -------------
// BM=256 x BN=128(x3 W), 8 waves (4M x 2N), per-wave 64x64 per W. Staged per
// 64-K window: A 32KB + B 48KB = 80KB for 2x the MFMA of the 128-row block
// -> total staged 512->320 MB. LDS 128KB (A single 32KB + B dbuf 2x48KB) ->
// 1 block/CU, grid 256 = 1 round. B_{k+1} issued one full window ahead
// (counted vmcnt(6)); only the 32KB A panel is issue->wait exposed/window.
// Per window: [ds_read+MFMA from As,Bs(cur)] -> s_barrier -> issue A_{k+1},
// B_{k+2}(into cur) -> vmcnt(6) -> s_barrier.
__global__ __launch_bounds__(512, 2)
void qkv_wide(const short* __restrict__ xb, const short* __restrict__ Wt,
              const float* __restrict__ bq, const float* __restrict__ bk,
              const float* __restrict__ bv,
              short* __restrict__ Qb, short* __restrict__ Kb,
              short* __restrict__ Vtb) {
    extern __shared__ short lds[];   // As 16384 | Bs0 24576 | Bs1 24576 shorts

    const int n0 = blockIdx.x * 128;   // col within each 1024-wide W output
    const int m0 = blockIdx.y * 256;   // row (8192 total)

    const int tid  = threadIdx.x;
    const int lane = tid & 63;
    const int wave = tid >> 6;
    const int wr   = (wave >> 1) * 64;   // 0,64,128,192
    const int wc   = (wave & 1) * 64;    // 0,64
    const int quad = lane >> 4;
    const int l16  = lane & 15;

    floatx4 acc[3][4][4];
#pragma unroll
    for (int w = 0; w < 3; w++)
#pragma unroll
        for (int i = 0; i < 4; i++)
#pragma unroll
            for (int j = 0; j < 4; j++) acc[w][i][j] = (floatx4){0.f, 0.f, 0.f, 0.f};

    // staging sources. A: 4 rounds of 512 thr (rows 0..255); B: per W 2 rounds
    // (rows 0..127). chunk g = p ^ (row&7), round-invariant per thread.
    const short* gA[4];
#pragma unroll
    for (int c = 0; c < 4; c++) {
        int idx = c * 512 + tid;
        int row = idx >> 3;
        int g = (idx & 7) ^ (row & 7);
        gA[c] = xb + (size_t)(m0 + row) * DM + g * 8;
    }
    const short* gB[2];
#pragma unroll
    for (int c = 0; c < 2; c++) {
        int idx = c * 512 + tid;
        int row = idx >> 3;
        int g = (idx & 7) ^ (row & 7);
        gB[c] = Wt + (size_t)(n0 + row) * DM + g * 8;
    }
    // wave-uniform LDS staging bases (HW adds lane*16B)
    short* lA  = lds + wave * 512;                // + c*4096
    short* lB0 = lds + 16384 + wave * 512;        // + bufsel*24576 + w*8192 + c*4096

    // frag read bases (XOR de-swizzle: row&7 == l16&7 for all frag rows)
    const short* fa[2]; int fbo[2];
#pragma unroll
    for (int h = 0; h < 2; h++) {
        int sw = ((h * 4 + quad) ^ (l16 & 7)) * 8;
        fa[h]  = &lds[(wr + l16) * 64 + sw];
        fbo[h] = (wc + l16) * 64 + sw;
    }
    const short* Bbase = lds + 16384;

    // ---- prologue: B_0 -> buf0, A_0, B_1 -> buf1 ----
#pragma unroll
    for (int w = 0; w < 3; w++)
#pragma unroll
        for (int c = 0; c < 2; c++)
            load16(gB[c] + (size_t)w * DM * DM, lB0 + w * 8192 + c * 4096);
#pragma unroll
    for (int c = 0; c < 4; c++) load16(gA[c], lA + c * 4096);
#pragma unroll
    for (int w = 0; w < 3; w++)
#pragma unroll
        for (int c = 0; c < 2; c++)
            load16(gB[c] + (size_t)w * DM * DM + 64, lB0 + 24576 + w * 8192 + c * 4096);
    asm volatile("s_waitcnt vmcnt(6)" ::: "memory");   // B_0 + A_0 landed
    __builtin_amdgcn_s_barrier();
    __builtin_amdgcn_sched_barrier(0);

    for (int k = 0; k < 16; k++) {
        const short* Bcur = Bbase + (k & 1) * 24576;
        // ---- compute window k ----
#pragma unroll
        for (int h = 0; h < 2; h++) {
            short8 af[4];
#pragma unroll
            for (int t = 0; t < 4; t++) af[t] = *(const short8*)(fa[h] + t * 1024);
#pragma unroll
            for (int w = 0; w < 3; w++) {
                short8 bf[4];
#pragma unroll
                for (int t = 0; t < 4; t++)
                    bf[t] = *(const short8*)(Bcur + w * 8192 + fbo[h] + t * 1024);
#pragma unroll
                for (int mt = 0; mt < 4; mt++)
#pragma unroll
                    for (int nt = 0; nt < 4; nt++)
                        acc[w][mt][nt] = __builtin_amdgcn_mfma_f32_16x16x32_bf16(
                            af[mt], bf[nt], acc[w][mt][nt], 0, 0, 0);
            }
        }
        if (k == 15) break;
        __builtin_amdgcn_s_barrier();              // all reads of As, Bs(cur) done
        __builtin_amdgcn_sched_barrier(0);
        // ---- issue A_{k+1} (exposed) and B_{k+2} (hidden, into cur buf) ----
        {
            const int koA = (k + 1) * 64;
#pragma unroll
            for (int c = 0; c < 4; c++) load16(gA[c] + koA, lA + c * 4096);
            if (k < 14) {
                const size_t koB = (size_t)(k + 2) * 64;
                short* dB = lds + 16384 + (k & 1) * 24576 + wave * 512;  // FIX: +wave*512
#pragma unroll
                for (int w = 0; w < 3; w++)
#pragma unroll
                    for (int c = 0; c < 2; c++)
                        load16(gB[c] + (size_t)w * DM * DM + koB,
                               dB + w * 8192 + c * 4096);
                asm volatile("s_waitcnt vmcnt(6)" ::: "memory");  // A_{k+1}+B_{k+1} in
            } else {
                asm volatile("s_waitcnt vmcnt(0)" ::: "memory");  // drain tail
            }
        }
        __builtin_amdgcn_s_barrier();
        __builtin_amdgcn_sched_barrier(0);
    }

    // ---- Q and K epilogues (direct row-major store) ----
#pragma unroll
    for (int w = 0; w < 2; w++) {
        short* out = w ? Kb : Qb;
        const float* bias = w ? bk : bq;
        float scale = w ? 1.0f : 0.03125f;   // fold 1/sqrt(1024) into Q
#pragma unroll
        for (int mt = 0; mt < 4; mt++)
#pragma unroll
            for (int nt = 0; nt < 4; nt++) {
                int col = n0 + wc + nt * 16 + l16;
                float bv_ = bias[col];
#pragma unroll
                for (int r = 0; r < 4; r++) {
                    int row = m0 + wr + mt * 16 + quad * 4 + r;
                    out[(size_t)row * DM + col] = f2bf((acc[w][mt][nt][r] + bv_) * scale);
                }
            }
    }

    // ---- V epilogue: write V^T into Vtb[b][d][s]; per-wave 64x64 LDS slice ----
    {
        __syncthreads();   // K-loop LDS fully retired (vmcnt==0); reuse as transpose buf
        int b = m0 >> 11;
        int sbase = (m0 & 2047) + wr;
        float bvv[4];
#pragma unroll
        for (int nt = 0; nt < 4; nt++) bvv[nt] = bv[n0 + wc + nt * 16 + l16];
        short* buf = lds + wave * 4608;   // 64 d-rows x 72 shorts each
        short* vt = Vtb + ((size_t)b * DM + n0 + wc) * S_LEN;
#pragma unroll
        for (int mt = 0; mt < 4; mt++)
#pragma unroll
            for (int nt = 0; nt < 4; nt++) {
                int c = nt * 16 + l16;
                short4v pk;
                pk.x = f2bf(acc[2][mt][nt][0] + bvv[nt]);
                pk.y = f2bf(acc[2][mt][nt][1] + bvv[nt]);
                pk.z = f2bf(acc[2][mt][nt][2] + bvv[nt]);
                pk.w = f2bf(acc[2][mt][nt][3] + bvv[nt]);
                *(short4v*)&buf[c * 72 + mt * 16 + quad * 4] = pk;
            }
        asm volatile("s_waitcnt lgkmcnt(0)" ::: "memory");
#pragma unroll
        for (int ps = 0; ps < 8; ps++) {
            int dl = ps * 8 + (lane >> 3);
            int sl = (lane & 7) * 8;
            short8 row = *(short8*)&buf[dl * 72 + sl];
            *(short8*)(vt + (size_t)dl * S_LEN + sbase + sl) = row;
        }
    }
}

// ---------------- score GEMM, wide tile 128x256, BK=64 (r6-proven) ---------
__global__ __launch_bounds__(256, 2)
void score_gemm(const short* __restrict__ Qb, const short* __restrict__ Kb,
                short* __restrict__ P, float* __restrict__ denom) {
    __shared__ short As[128 * 64];   // 16 KB
    __shared__ short Bs[256 * 64];   // 32 KB

    const int bid = blockIdx.x;
    const int xcd = bid & 7;
    const int w   = bid >> 3;        // 0..35
    const int b   = w / 9;
    const int s   = w % 9;
    const int cx  = (xcd + 2) >> 1;  // blocks in row it=xcd: ceil((xcd+1)/2)
    const int it  = (s < cx) ? xcd : 15 - xcd;
    const int jt2 = (s < cx) ? s : s - cx;
    const int m0  = it * 128;
    const int n0  = jt2 * 256;

    const short* A  = Qb + (size_t)b * S_LEN * DM;
    const short* Bt = Kb + (size_t)b * S_LEN * DM;

    const int tid  = threadIdx.x;
    const int lane = tid & 63;
    const int wave = tid >> 6;
    const int wr   = (wave >> 1) * 64;    // 0,64
    const int wc   = (wave & 1) * 128;    // 0,128
    const int quad = lane >> 4;
    const int l16  = lane & 15;

    floatx4 acc[4][8];
#pragma unroll
    for (int i = 0; i < 4; i++)
#pragma unroll
        for (int j = 0; j < 8; j++) acc[i][j] = (floatx4){0.f, 0.f, 0.f, 0.f};

    const int g = (tid & 7) ^ ((tid >> 3) & 7);
    const short* gA0 = A  + (size_t)(m0 + (tid >> 3)) * DM + g * 8;
    const short* gB0 = Bt + (size_t)(n0 + (tid >> 3)) * DM + g * 8;
    short* lA0 = &As[wave * 512];   // + c*2048
    short* lB0 = &Bs[wave * 512];

    const short* fa[2]; const short* fb[2];
#pragma unroll
    for (int h = 0; h < 2; h++) {
        int sw = ((h * 4 + quad) ^ (l16 & 7)) * 8;
        fa[h] = &As[(wr + l16) * 64 + sw];
        fb[h] = &Bs[(wc + l16) * 64 + sw];
    }

    for (int k0 = 0; k0 < DM; k0 += 64) {
#pragma unroll
        for (int c = 0; c < 4; c++) load16(gA0 + (size_t)c * 32 * DM, lA0 + c * 2048);
#pragma unroll
        for (int c = 0; c < 8; c++) load16(gB0 + (size_t)c * 32 * DM, lB0 + c * 2048);
        gA0 += 64; gB0 += 64;
        __syncthreads();

#pragma unroll
        for (int h = 0; h < 2; h++) {
            short8 af[4];
#pragma unroll
            for (int t = 0; t < 4; t++) af[t] = *(const short8*)(fa[h] + t * 1024);
            short8 bf[8];
#pragma unroll
            for (int t = 0; t < 8; t++) bf[t] = *(const short8*)(fb[h] + t * 1024);
#pragma unroll
            for (int mt = 0; mt < 4; mt++)
#pragma unroll
                for (int nt = 0; nt < 8; nt++)
                    acc[mt][nt] = __builtin_amdgcn_mfma_f32_16x16x32_bf16(
                        af[mt], bf[nt], acc[mt][nt], 0, 0, 0);
        }
        __syncthreads();
    }

    short* out = P + (size_t)b * S_LEN * S_LEN;
    float* dsum = denom + (size_t)b * S_LEN;
#pragma unroll
    for (int mt = 0; mt < 4; mt++) {
#pragma unroll
        for (int r = 0; r < 4; r++) {
            int row = m0 + wr + mt * 16 + quad * 4 + r;
            float psum = 0.f;
#pragma unroll
            for (int nt = 0; nt < 8; nt++) {
                int col = n0 + wc + nt * 16 + l16;
                float e = (col <= row) ? __expf(acc[mt][nt][r]) : 0.f;
                out[(size_t)row * S_LEN + col] = f2bf(e);
                psum += e;
            }
#pragma unroll
            for (int off = 8; off > 0; off >>= 1)
                psum += __shfl_down(psum, off, 16);
            if (l16 == 0) atomicAdd(&dsum[row], psum);
        }
    }
}

// ---------------- PV GEMM, BK=128, XCD-wedge grid (r4-proven) --------------
__global__ __launch_bounds__(256, 2)
void pv_gemm(const short* __restrict__ P, const short* __restrict__ Vtb,
             const float* __restrict__ denom, float* __restrict__ O) {
    __shared__ short As[16384];
    __shared__ short Bs[16384];
    int bid  = blockIdx.x;
    int xcd  = bid & 7;
    int wi   = bid >> 3;              // 0..63
    int b    = xcd >> 1;
    int dgrp = xcd & 1;
    int half = wi >> 5;               // 0: heavy (it 15..8), 1: light (it 0..7)
    int r    = (wi >> 2) & 7;
    int dl   = wi & 3;
    int it   = half ? r : 15 - r;
    int n0   = (dgrp * 4 + dl) * 128; // d
    int m0   = it * 128;              // query rows
    int kLen = (it + 1) * 128;        // causal clip
    const short* A  = P   + (size_t)b * S_LEN * S_LEN;
    const short* Bt = Vtb + (size_t)b * DM * S_LEN;

    floatx4 acc[4][4];
#pragma unroll
    for (int i = 0; i < 4; i++)
#pragma unroll
        for (int j = 0; j < 4; j++) acc[i][j] = (floatx4){0.f, 0.f, 0.f, 0.f};

    gemm_core128(A, Bt, S_LEN, S_LEN, kLen, m0, n0, acc, As, Bs);

    float* out = O + (size_t)b * S_LEN * DM;
    const float* dsum = denom + (size_t)b * S_LEN;
    const int lane = threadIdx.x & 63, wave = threadIdx.x >> 6;
    const int wr = (wave >> 1) * 64, wc = (wave & 1) * 64;
    const int quad = lane >> 4, l16 = lane & 15;
#pragma unroll
    for (int mt = 0; mt < 4; mt++) {
#pragma unroll
        for (int r2 = 0; r2 < 4; r2++) {
            int row = m0 + wr + mt * 16 + quad * 4 + r2;
            float inv = 1.0f / dsum[row];
#pragma unroll
            for (int nt = 0; nt < 4; nt++) {
                int col = n0 + wc + nt * 16 + l16;
                out[(size_t)row * DM + col] = acc[mt][nt][r2] * inv;
            }
        }
    }
}

// ---------------- launch ----------------
extern "C" void kernel_launch(void* const* d_in, const int* in_sizes, int n_in,
                              void* d_out, int out_size, void* d_ws, size_t ws_size,
                              hipStream_t stream) {
    const float* x  = (const float*)d_in[0];
    const float* Wq = (const float*)d_in[1];
    const float* bq = (const float*)d_in[2];
    const float* Wk = (const float*)d_in[3];
    const float* bk = (const float*)d_in[4];
    const float* Wv = (const float*)d_in[5];
    const float* bv = (const float*)d_in[6];
    float* out = (float*)d_out;

    char* ws = (char*)d_ws;
    const size_t MB = 1u << 20;
    short* xb    = (short*)(ws + 0);          // 16 MB  [8192][1024] bf16
    short* Wt    = (short*)(ws + 16 * MB);    //  6 MB  [3][1024][1024] bf16 (n-major)
    short* Qb    = (short*)(ws + 22 * MB);    // 16 MB
    short* Kb    = (short*)(ws + 38 * MB);    // 16 MB
    short* Vtb   = (short*)(ws + 54 * MB);    // 16 MB  [b][d][s]
    short* P     = (short*)(ws + 70 * MB);    // 32 MB  [b][s][s] bf16 = exp(s)
    float* denom = (float*)(ws + 102 * MB);   // 32 KB  [b][s] fp32 row sums
    // total ~102 MB

    static bool attr_set = false;
    if (!attr_set) {
        hipFuncSetAttribute(reinterpret_cast<const void*>(qkv_wide),
                            hipFuncAttributeMaxDynamicSharedMemorySize, 131072);
        attr_set = true;
    }

    hipMemsetAsync(denom, 0, (size_t)NB * S_LEN * sizeof(float), stream);
    prep<<<dim3(8960), dim3(256), 0, stream>>>(x, Wq, Wk, Wv, xb, Wt);
    qkv_wide<<<dim3(8, 32), dim3(512), 131072, stream>>>(xb, Wt, bq, bk, bv, Qb, Kb, Vtb);
    score_gemm<<<dim3(288), dim3(256), 0, stream>>>(Qb, Kb, P, denom);
    pv_gemm<<<dim3(512), dim3(256), 0, stream>>>(P, Vtb, denom, out);
}

// Round 9
// 208.804 us; speedup vs baseline: 1.0545x; 1.0545x over previous
//
#include <hip/hip_runtime.h>
#include <hip/hip_bf16.h>

#define S_LEN 2048
#define DM 1024
#define NB 4

typedef __attribute__((ext_vector_type(8))) short short8;
typedef __attribute__((ext_vector_type(4))) short short4v;
typedef __attribute__((ext_vector_type(4))) float floatx4;

__device__ inline short f2bf(float f) {
    union { float f; unsigned u; } v; v.f = f;
    unsigned r = 0x7fffu + ((v.u >> 16) & 1u);
    return (short)((v.u + r) >> 16);
}

// async global->LDS 16B per lane; lds dest must be wave-uniform base (+lane*16 by HW)
__device__ inline void load16(const short* g, short* l) {
    __builtin_amdgcn_global_load_lds(
        (const __attribute__((address_space(1))) void*)g,
        (__attribute__((address_space(3))) void*)l,
        16, 0, 0);
}

// ---------------- BK=128 GEMM core (pv; r4-proven) -------------------------
__device__ inline void gemm_core128(const short* __restrict__ A,
                                    const short* __restrict__ Bt,
                                    int lda, int ldb, int kLen,
                                    int m0, int n0, floatx4 acc[4][4],
                                    short* As, short* Bs) {
    const int tid  = threadIdx.x;
    const int lane = tid & 63;
    const int wave = tid >> 6;
    const int wr   = (wave >> 1) * 64;
    const int wc   = (wave & 1) * 64;
    const int quad = lane >> 4;
    const int l16  = lane & 15;

    const int srow = tid >> 4;
    const int g    = (tid & 15) ^ srow;
    const short* gA0 = A  + (size_t)(m0 + srow) * lda + g * 8;
    const short* gB0 = Bt + (size_t)(n0 + srow) * ldb + g * 8;
    short* lA0 = &As[wave * 512];
    short* lB0 = &Bs[wave * 512];

    const short* fa[4]; const short* fb[4];
#pragma unroll
    for (int h = 0; h < 4; h++) {
        int sw = ((h * 4 + quad) ^ l16) * 8;
        fa[h] = &As[(wr + l16) * 128 + sw];
        fb[h] = &Bs[(wc + l16) * 128 + sw];
    }

    for (int k0 = 0; k0 < kLen; k0 += 128) {
#pragma unroll
        for (int c = 0; c < 8; c++) load16(gA0 + (size_t)c * 16 * lda, lA0 + c * 2048);
#pragma unroll
        for (int c = 0; c < 8; c++) load16(gB0 + (size_t)c * 16 * ldb, lB0 + c * 2048);
        gA0 += 128; gB0 += 128;
        __syncthreads();

#pragma unroll
        for (int h = 0; h < 4; h++) {
            short8 af[4], bf[4];
#pragma unroll
            for (int t = 0; t < 4; t++) af[t] = *(const short8*)(fa[h] + t * 2048);
#pragma unroll
            for (int t = 0; t < 4; t++) bf[t] = *(const short8*)(fb[h] + t * 2048);
#pragma unroll
            for (int mt = 0; mt < 4; mt++)
#pragma unroll
                for (int nt = 0; nt < 4; nt++)
                    acc[mt][nt] = __builtin_amdgcn_mfma_f32_16x16x32_bf16(
                        af[mt], bf[nt], acc[mt][nt], 0, 0, 0);
        }
        __syncthreads();
    }
}

// ---------------- merged prep: Wt transpose+cast, x cast -------------------
__global__ void prep(const float* __restrict__ x,
                     const float* __restrict__ Wq, const float* __restrict__ Wk,
                     const float* __restrict__ Wv,
                     short* __restrict__ xb, short* __restrict__ Wt) {
    __shared__ float t[64][65];
    int bid = blockIdx.x, tid = threadIdx.x;
    if (bid < 768) {
        // W [k][n] fp32 -> Wt [n][k] bf16 (64x64 tiles)
        int w = bid >> 8, tl = bid & 255;
        const float* W = (w == 0) ? Wq : (w == 1) ? Wk : Wv;
        short* out = Wt + (size_t)w * DM * DM;
        int bx = (tl & 15) * 64;   // n
        int by = (tl >> 4) * 64;   // k
        int tx = tid & 63, ty = tid >> 6;
        for (int r = ty; r < 64; r += 4)
            t[r][tx] = W[(size_t)(by + r) * DM + bx + tx];
        __syncthreads();
        for (int r = ty; r < 64; r += 4)
            out[(size_t)(bx + r) * DM + by + tx] = f2bf(t[tx][r]);
    } else {
        // x fp32 -> bf16, float4-wide
        int i = (bid - 768) * 256 + tid;
        float4 v = ((const float4*)x)[i];
        short4v o;
        o.x = f2bf(v.x); o.y = f2bf(v.y); o.z = f2bf(v.z); o.w = f2bf(v.w);
        ((short4v*)xb)[i] = o;
    }
}

// ---------------- fused QKV GEMM, BK=64 (r0/r6 version, ~954 TF) -----------
__global__ __launch_bounds__(256, 2)
void qkv_fused(const short* __restrict__ xb, const short* __restrict__ Wt,
               const float* __restrict__ bq, const float* __restrict__ bk,
               const float* __restrict__ bv,
               short* __restrict__ Qb, short* __restrict__ Kb,
               short* __restrict__ Vtb) {
    __shared__ short As[8192];        // 128x64 staging; also V-transpose buf (4608)
    __shared__ short Bs[3 * 8192];
    int n0 = blockIdx.x * 128;
    int m0 = blockIdx.y * 128;

    const int tid  = threadIdx.x;
    const int lane = tid & 63;
    const int wave = tid >> 6;
    const int wr   = (wave >> 1) * 64;
    const int wc   = (wave & 1) * 64;
    const int quad = lane >> 4;
    const int l16  = lane & 15;

    floatx4 acc[3][4][4];
#pragma unroll
    for (int w = 0; w < 3; w++)
#pragma unroll
        for (int i = 0; i < 4; i++)
#pragma unroll
            for (int j = 0; j < 4; j++) acc[w][i][j] = (floatx4){0.f, 0.f, 0.f, 0.f};

    const short* gA[4]; const short* gW[4];
    short* lA[4]; short* lB[4];
#pragma unroll
    for (int c = 0; c < 4; c++) {
        int idx = c * 256 + tid;
        int row = idx >> 3;
        int g = (idx & 7) ^ (row & 7);
        gA[c] = xb + (size_t)(m0 + row) * DM + g * 8;
        gW[c] = Wt + (size_t)(n0 + row) * DM + g * 8;
        int lbase = (c * 256 + wave * 64) * 8;
        lA[c] = &As[lbase];
        lB[c] = &Bs[lbase];
    }

    const short* fa[2]; const short* fb[2];
#pragma unroll
    for (int h = 0; h < 2; h++) {
        int sw = ((h * 4 + quad) ^ (l16 & 7)) * 8;
        fa[h] = &As[(wr + l16) * 64 + sw];
        fb[h] = &Bs[(wc + l16) * 64 + sw];
    }

    for (int k0 = 0; k0 < DM; k0 += 64) {
#pragma unroll
        for (int c = 0; c < 4; c++) load16(gA[c], lA[c]);
#pragma unroll
        for (int w = 0; w < 3; w++)
#pragma unroll
            for (int c = 0; c < 4; c++)
                load16(gW[c] + (size_t)w * DM * DM, lB[c] + w * 8192);
#pragma unroll
        for (int c = 0; c < 4; c++) { gA[c] += 64; gW[c] += 64; }
        __syncthreads();

#pragma unroll
        for (int h = 0; h < 2; h++) {
            short8 af[4];
#pragma unroll
            for (int t = 0; t < 4; t++) af[t] = *(const short8*)(fa[h] + t * 1024);
#pragma unroll
            for (int w = 0; w < 3; w++) {
                short8 bf[4];
#pragma unroll
                for (int t = 0; t < 4; t++)
                    bf[t] = *(const short8*)(fb[h] + w * 8192 + t * 1024);
#pragma unroll
                for (int mt = 0; mt < 4; mt++)
#pragma unroll
                    for (int nt = 0; nt < 4; nt++)
                        acc[w][mt][nt] = __builtin_amdgcn_mfma_f32_16x16x32_bf16(
                            af[mt], bf[nt], acc[w][mt][nt], 0, 0, 0);
            }
        }
        __syncthreads();
    }

    // ---- Q and K epilogues (direct row-major store) ----
#pragma unroll
    for (int w = 0; w < 2; w++) {
        short* out = w ? Kb : Qb;
        const float* bias = w ? bk : bq;
        float scale = w ? 1.0f : 0.03125f;   // fold 1/sqrt(1024) into Q
#pragma unroll
        for (int mt = 0; mt < 4; mt++)
#pragma unroll
            for (int nt = 0; nt < 4; nt++) {
                int col = n0 + wc + nt * 16 + l16;
                float bv_ = bias[col];
#pragma unroll
                for (int r = 0; r < 4; r++) {
                    int row = m0 + wr + mt * 16 + quad * 4 + r;
                    out[(size_t)row * DM + col] = f2bf((acc[w][mt][nt][r] + bv_) * scale);
                }
            }
    }

    // ---- V epilogue: write V^T into Vtb[b][d][s] via per-wave 64x64 LDS pass ----
    {
        int b = m0 >> 11;
        int sbase = (m0 & 2047) + wr;
        float bvv[4];
#pragma unroll
        for (int nt = 0; nt < 4; nt++) bvv[nt] = bv[n0 + wc + nt * 16 + l16];
        short* buf = (wave & 1) ? Bs : As;   // 64 d-rows x 72 (stride 144B, 16B-aligned)
        short* vt = Vtb + ((size_t)b * DM + n0 + wc) * S_LEN;
#pragma unroll
        for (int p = 0; p < 2; p++) {
            __syncthreads();
            if ((wave >> 1) == p) {
#pragma unroll
                for (int mt = 0; mt < 4; mt++)
#pragma unroll
                    for (int nt = 0; nt < 4; nt++) {
                        int c = nt * 16 + l16;
                        short4v pk;
                        pk.x = f2bf(acc[2][mt][nt][0] + bvv[nt]);
                        pk.y = f2bf(acc[2][mt][nt][1] + bvv[nt]);
                        pk.z = f2bf(acc[2][mt][nt][2] + bvv[nt]);
                        pk.w = f2bf(acc[2][mt][nt][3] + bvv[nt]);
                        *(short4v*)&buf[c * 72 + mt * 16 + quad * 4] = pk;
                    }
                asm volatile("s_waitcnt lgkmcnt(0)" ::: "memory");
#pragma unroll
                for (int ps = 0; ps < 8; ps++) {
                    int dl = ps * 8 + (lane >> 3);
                    int sl = (lane & 7) * 8;
                    short8 row = *(short8*)&buf[dl * 72 + sl];
                    *(short8*)(vt + (size_t)dl * S_LEN + sbase + sl) = row;
                }
            }
        }
    }
}

// ---------------- score GEMM, 128x256 tile, BK=64, B double-buffered -------
// r6 tile/grid/epilogue; staging now: A single 16KB + B dbuf 2x32KB = 80KB
// -> still 2 blocks/CU, and the 224 solo-CU blocks get their B-latency
// (2/3 of staged bytes) hidden under compute via counted vmcnt (r8-proven
// ledger). Per window: compute(buf k&1) -> barrier -> issue A_{k+1} +
// B_{k+2}(into buf k&1) -> vmcnt(8) [retires A_{k+1}+B_{k+1}, keeps B_{k+2}
// in flight] -> barrier.
__global__ __launch_bounds__(256, 2)
void score_gemm(const short* __restrict__ Qb, const short* __restrict__ Kb,
                short* __restrict__ P, float* __restrict__ denom) {
    extern __shared__ short lds[];   // As 8192 | Bs0 16384 | Bs1 16384 shorts

    const int bid = blockIdx.x;
    const int xcd = bid & 7;
    const int w   = bid >> 3;        // 0..35
    const int b   = w / 9;
    const int s   = w % 9;
    const int cx  = (xcd + 2) >> 1;  // blocks in row it=xcd: ceil((xcd+1)/2)
    const int it  = (s < cx) ? xcd : 15 - xcd;
    const int jt2 = (s < cx) ? s : s - cx;
    const int m0  = it * 128;
    const int n0  = jt2 * 256;

    const short* A  = Qb + (size_t)b * S_LEN * DM;
    const short* Bt = Kb + (size_t)b * S_LEN * DM;

    const int tid  = threadIdx.x;
    const int lane = tid & 63;
    const int wave = tid >> 6;
    const int wr   = (wave >> 1) * 64;    // 0,64
    const int wc   = (wave & 1) * 128;    // 0,128
    const int quad = lane >> 4;
    const int l16  = lane & 15;

    floatx4 acc[4][8];
#pragma unroll
    for (int i = 0; i < 4; i++)
#pragma unroll
        for (int j = 0; j < 8; j++) acc[i][j] = (floatx4){0.f, 0.f, 0.f, 0.f};

    // staging: row = c*32 + (tid>>3); chunk g = (tid&7)^((tid>>3)&7)
    const int g = (tid & 7) ^ ((tid >> 3) & 7);
    const short* gA0 = A  + (size_t)(m0 + (tid >> 3)) * DM + g * 8;
    const short* gB0 = Bt + (size_t)(n0 + (tid >> 3)) * DM + g * 8;
    short* lA = lds + wave * 512;            // + c*2048            (A: 4 rounds)
    short* lB = lds + 8192 + wave * 512;     // + buf*16384 + c*2048 (B: 8 rounds)

    const short* fa[2]; int fbo[2];
#pragma unroll
    for (int h = 0; h < 2; h++) {
        int sw = ((h * 4 + quad) ^ (l16 & 7)) * 8;
        fa[h]  = &lds[(wr + l16) * 64 + sw];
        fbo[h] = 8192 + (wc + l16) * 64 + sw;
    }

    // ---- prologue: A_0, B_0 -> buf0; B_1 -> buf1 ----
#pragma unroll
    for (int c = 0; c < 4; c++) load16(gA0 + (size_t)c * 32 * DM, lA + c * 2048);
#pragma unroll
    for (int c = 0; c < 8; c++) load16(gB0 + (size_t)c * 32 * DM, lB + c * 2048);
#pragma unroll
    for (int c = 0; c < 8; c++) load16(gB0 + 64 + (size_t)c * 32 * DM, lB + 16384 + c * 2048);
    asm volatile("s_waitcnt vmcnt(8)" ::: "memory");   // A_0 + B_0 landed
    __builtin_amdgcn_s_barrier();
    __builtin_amdgcn_sched_barrier(0);

    for (int k = 0; k < 16; k++) {
        const int bo = (k & 1) * 16384;
        // ---- compute window k from As + Bs[k&1] ----
#pragma unroll
        for (int h = 0; h < 2; h++) {
            short8 af[4];
#pragma unroll
            for (int t = 0; t < 4; t++) af[t] = *(const short8*)(fa[h] + t * 1024);
            short8 bf[8];
#pragma unroll
            for (int t = 0; t < 8; t++)
                bf[t] = *(const short8*)(lds + fbo[h] + bo + t * 1024);
#pragma unroll
            for (int mt = 0; mt < 4; mt++)
#pragma unroll
                for (int nt = 0; nt < 8; nt++)
                    acc[mt][nt] = __builtin_amdgcn_mfma_f32_16x16x32_bf16(
                        af[mt], bf[nt], acc[mt][nt], 0, 0, 0);
        }
        if (k == 15) break;
        __builtin_amdgcn_s_barrier();              // reads of As, Bs[k&1] done
        __builtin_amdgcn_sched_barrier(0);
        // ---- issue A_{k+1} (exposed) and B_{k+2} (hidden, into buf k&1) ----
        {
            const int koA = (k + 1) * 64;
#pragma unroll
            for (int c = 0; c < 4; c++)
                load16(gA0 + koA + (size_t)c * 32 * DM, lA + c * 2048);
            if (k < 14) {
                const int koB = (k + 2) * 64;
#pragma unroll
                for (int c = 0; c < 8; c++)
                    load16(gB0 + koB + (size_t)c * 32 * DM, lB + bo + c * 2048);
                asm volatile("s_waitcnt vmcnt(8)" ::: "memory");  // A_{k+1}+B_{k+1} in
            } else {
                asm volatile("s_waitcnt vmcnt(0)" ::: "memory");  // drain tail
            }
        }
        __builtin_amdgcn_s_barrier();
        __builtin_amdgcn_sched_barrier(0);
    }

    short* out = P + (size_t)b * S_LEN * S_LEN;
    float* dsum = denom + (size_t)b * S_LEN;
#pragma unroll
    for (int mt = 0; mt < 4; mt++) {
#pragma unroll
        for (int r = 0; r < 4; r++) {
            int row = m0 + wr + mt * 16 + quad * 4 + r;
            float psum = 0.f;
#pragma unroll
            for (int nt = 0; nt < 8; nt++) {
                int col = n0 + wc + nt * 16 + l16;
                float e = (col <= row) ? __expf(acc[mt][nt][r]) : 0.f;
                out[(size_t)row * S_LEN + col] = f2bf(e);
                psum += e;
            }
#pragma unroll
            for (int off = 8; off > 0; off >>= 1)
                psum += __shfl_down(psum, off, 16);
            if (l16 == 0) atomicAdd(&dsum[row], psum);
        }
    }
}

// ---------------- PV GEMM, BK=128, XCD-wedge grid (r4-proven) --------------
__global__ __launch_bounds__(256, 2)
void pv_gemm(const short* __restrict__ P, const short* __restrict__ Vtb,
             const float* __restrict__ denom, float* __restrict__ O) {
    __shared__ short As[16384];
    __shared__ short Bs[16384];
    int bid  = blockIdx.x;
    int xcd  = bid & 7;
    int wi   = bid >> 3;              // 0..63
    int b    = xcd >> 1;
    int dgrp = xcd & 1;
    int half = wi >> 5;               // 0: heavy (it 15..8), 1: light (it 0..7)
    int r    = (wi >> 2) & 7;
    int dl   = wi & 3;
    int it   = half ? r : 15 - r;
    int n0   = (dgrp * 4 + dl) * 128; // d
    int m0   = it * 128;              // query rows
    int kLen = (it + 1) * 128;        // causal clip
    const short* A  = P   + (size_t)b * S_LEN * S_LEN;
    const short* Bt = Vtb + (size_t)b * DM * S_LEN;

    floatx4 acc[4][4];
#pragma unroll
    for (int i = 0; i < 4; i++)
#pragma unroll
        for (int j = 0; j < 4; j++) acc[i][j] = (floatx4){0.f, 0.f, 0.f, 0.f};

    gemm_core128(A, Bt, S_LEN, S_LEN, kLen, m0, n0, acc, As, Bs);

    float* out = O + (size_t)b * S_LEN * DM;
    const float* dsum = denom + (size_t)b * S_LEN;
    const int lane = threadIdx.x & 63, wave = threadIdx.x >> 6;
    const int wr = (wave >> 1) * 64, wc = (wave & 1) * 64;
    const int quad = lane >> 4, l16 = lane & 15;
#pragma unroll
    for (int mt = 0; mt < 4; mt++) {
#pragma unroll
        for (int r2 = 0; r2 < 4; r2++) {
            int row = m0 + wr + mt * 16 + quad * 4 + r2;
            float inv = 1.0f / dsum[row];
#pragma unroll
            for (int nt = 0; nt < 4; nt++) {
                int col = n0 + wc + nt * 16 + l16;
                out[(size_t)row * DM + col] = acc[mt][nt][r2] * inv;
            }
        }
    }
}

// ---------------- launch ----------------
extern "C" void kernel_launch(void* const* d_in, const int* in_sizes, int n_in,
                              void* d_out, int out_size, void* d_ws, size_t ws_size,
                              hipStream_t stream) {
    const float* x  = (const float*)d_in[0];
    const float* Wq = (const float*)d_in[1];
    const float* bq = (const float*)d_in[2];
    const float* Wk = (const float*)d_in[3];
    const float* bk = (const float*)d_in[4];
    const float* Wv = (const float*)d_in[5];
    const float* bv = (const float*)d_in[6];
    float* out = (float*)d_out;

    char* ws = (char*)d_ws;
    const size_t MB = 1u << 20;
    short* xb    = (short*)(ws + 0);          // 16 MB  [8192][1024] bf16
    short* Wt    = (short*)(ws + 16 * MB);    //  6 MB  [3][1024][1024] bf16 (n-major)
    short* Qb    = (short*)(ws + 22 * MB);    // 16 MB
    short* Kb    = (short*)(ws + 38 * MB);    // 16 MB
    short* Vtb   = (short*)(ws + 54 * MB);    // 16 MB  [b][d][s]
    short* P     = (short*)(ws + 70 * MB);    // 32 MB  [b][s][s] bf16 = exp(s)
    float* denom = (float*)(ws + 102 * MB);   // 32 KB  [b][s] fp32 row sums
    // total ~102 MB

    static bool attr_set = false;
    if (!attr_set) {
        hipFuncSetAttribute(reinterpret_cast<const void*>(score_gemm),
                            hipFuncAttributeMaxDynamicSharedMemorySize, 81920);
        attr_set = true;
    }

    hipMemsetAsync(denom, 0, (size_t)NB * S_LEN * sizeof(float), stream);
    prep<<<dim3(8960), dim3(256), 0, stream>>>(x, Wq, Wk, Wv, xb, Wt);
    qkv_fused<<<dim3(8, 64), dim3(256), 0, stream>>>(xb, Wt, bq, bk, bv, Qb, Kb, Vtb);
    score_gemm<<<dim3(288), dim3(256), 81920, stream>>>(Qb, Kb, P, denom);
    pv_gemm<<<dim3(512), dim3(256), 0, stream>>>(P, Vtb, denom, out);
}